// Round 12
// baseline (145.477 us; speedup 1.0000x reference)
//
#include <hip/hip_runtime.h>
#include <math.h>

namespace {

constexpr int   kB     = 16;
constexpr int   kA     = 65536;
constexpr int   kM     = 32;
constexpr int   kC     = 20;
constexpr float kImg   = 600.0f;
constexpr int   kBlock = 256;

constexpr int kAnchPerThread = 4;
constexpr int kAnchPerBlock  = kBlock * kAnchPerThread;  // 1024
constexpr int kGridX         = kA / kAnchPerBlock;       // 64
constexpr int kNBlocks       = kGridX * kB;              // 1024 (ws: 1024*3 floats)
constexpr int kF4PerChunk    = kBlock * kC / 4;          // 1280 float4s per 256-anchor chunk

__device__ __forceinline__ float smooth_l1(float d) {
    float ad = fabsf(d);
    return ad < 1.0f ? 0.5f * d * d : ad - 0.5f;
}

// f0(x) = sigmoid(x)^2 * softplus(x)  (t=0 focal term; t=1 is f0(-x)).
// Single definition everywhere -> stream/correction terms cancel exactly.
__device__ __forceinline__ float f0s(float x) {
    float u  = __expf(-x);
    float d  = 1.0f + u;
    float s  = __builtin_amdgcn_rcpf(d);       // sigmoid(x)
    float sp = x + __logf(d);                  // softplus(x)
    return s * s * sp;
}

// Lessons ledger:
//  R2: no launch_bounds min-waves arg (",6" -> VGPR cap 40 -> 359 MB spill).
//  R4: even/odd role split in one kernel -> shared-regalloc VGPR cliff.
//  R7/R8: row bodies in every wave (55us); same-address atomics (371us).
//  R9: IoU loop LDS accounting -> share sbox/sarea reads across 4 anchors.
//  R10 (43us main): row-per-thread cls loads are STRIDE-80B across the wave
//      (~5x cacheline transactions per instr). THIS round: unit-stride chunk
//      loads (consecutive lanes -> consecutive float4s) + slive[1024] LDS
//      mask (f/5 magic-mul, broadcast reads), double-buffered chunks.
__global__ __launch_bounds__(kBlock) void retina_main(
    const float* __restrict__ loc_preds,   // [B, A, 4]
    const float* __restrict__ cls_preds,   // [B, A, C]
    const float* __restrict__ iou_boxes,   // [A, 4] xywh
    const float* __restrict__ targets,     // [B*M, 6]
    float* __restrict__ partial)           // [kNBlocks][3]
{
    __shared__ float4 sbox[kM];    // x1, y1, x2+1, y2+1 (pixels)
    __shared__ float4 sxywh[kM];   // cx, cy, w, h (pixels)
    __shared__ float  sarea[kM];   // target area (+1 convention)
    __shared__ int    slab[kM];
    __shared__ float  slive[kAnchPerBlock];   // 0 if ignored, else 1
    __shared__ float  sred[3][kBlock / 64];

    const int b   = blockIdx.y;
    const int ab  = blockIdx.x * kAnchPerBlock;
    const int tid = threadIdx.x;
    const int a0  = ab + tid;                 // thread's anchors: a0 + K*256

    if (tid < kM) {
        const float* t = targets + ((size_t)(b * kM + tid)) * 6;
        float cx = t[2] * kImg, cy = t[3] * kImg;
        float w  = t[4] * kImg, h  = t[5] * kImg;
        float x1  = cx - w * 0.5f,        y1  = cy - h * 0.5f;
        float x2p = cx + w * 0.5f + 1.0f, y2p = cy + h * 0.5f + 1.0f;
        sbox[tid]  = make_float4(x1, y1, x2p, y2p);
        sxywh[tid] = make_float4(cx, cy, w, h);
        sarea[tid] = (x2p - x1) * (y2p - y1);
        slab[tid]  = (int)t[1];
    }

    // Anchor rows (16B/lane unit-stride) -- issue before the barrier.
    const float4 an0 = *(const float4*)(iou_boxes + (size_t)(a0 + 0 * kBlock) * 4);
    const float4 an1 = *(const float4*)(iou_boxes + (size_t)(a0 + 1 * kBlock) * 4);
    const float4 an2 = *(const float4*)(iou_boxes + (size_t)(a0 + 2 * kBlock) * 4);
    const float4 an3 = *(const float4*)(iou_boxes + (size_t)(a0 + 3 * kBlock) * 4);

    // Block's cls slab: 1024 anchors * 20 floats = 5120 float4s, unit-stride.
    const float4* cb4 = (const float4*)(cls_preds + ((size_t)b * kA + ab) * kC);
    const float*  cb  = (const float*)cb4;

#define LOADCHUNK(P0, P1, P2, P3, P4, C) { \
    const float4* _p = cb4 + (C) * kF4PerChunk + tid; \
    P0 = _p[0]; P1 = _p[256]; P2 = _p[512]; P3 = _p[768]; P4 = _p[1024]; }

    // Chunk 0 issued HERE: latency hides under the IoU loop.
    float4 p0, p1, p2, p3, p4;
    LOADCHUNK(p0, p1, p2, p3, p4, 0)

    __syncthreads();

#define DERIVE(K, AN) \
    const float x1_##K = AN.x - AN.z * 0.5f; \
    const float y1_##K = AN.y - AN.w * 0.5f; \
    const float x2_##K = AN.x + AN.z * 0.5f + 1.0f; \
    const float y2_##K = AN.y + AN.w * 0.5f + 1.0f; \
    const float ar_##K = (x2_##K - x1_##K) * (y2_##K - y1_##K);
    DERIVE(0, an0) DERIVE(1, an1) DERIVE(2, an2) DERIVE(3, an3)
#undef DERIVE

    float bs0 = -1.0f, bs1 = -1.0f, bs2 = -1.0f, bs3 = -1.0f;
    int   m0 = 0, m1 = 0, m2 = 0, m3 = 0;

    // ---- IoU argmax: ONE sbox/sarea read serves FOUR anchors ----
#pragma unroll 8
    for (int m = 0; m < kM; ++m) {
        const float4 q  = sbox[m];
        const float  ar = sarea[m];
#define IOU(K) { \
        float lx = fmaxf(x1_##K, q.x); \
        float ly = fmaxf(y1_##K, q.y); \
        float rx = fminf(x2_##K, q.z); \
        float ry = fminf(y2_##K, q.w); \
        float w  = fmaxf(rx - lx, 0.0f); \
        float h  = fmaxf(ry - ly, 0.0f); \
        float inter = w * h; \
        float uni   = ar_##K + ar - inter; \
        float iou   = inter * __builtin_amdgcn_rcpf(uni); \
        if (iou > bs##K) { bs##K = iou; m##K = m; } }
        IOU(0) IOU(1) IOU(2) IOU(3)
#undef IOU
    }

    const bool pos0 = bs0 >= 0.5f, ign0 = (bs0 > 0.4f) && !pos0;
    const bool pos1 = bs1 >= 0.5f, ign1 = (bs1 > 0.4f) && !pos1;
    const bool pos2 = bs2 >= 0.5f, ign2 = (bs2 > 0.4f) && !pos2;
    const bool pos3 = bs3 >= 0.5f, ign3 = (bs3 > 0.4f) && !pos3;

    slive[tid + 0 * kBlock] = ign0 ? 0.0f : 1.0f;
    slive[tid + 1 * kBlock] = ign1 ? 0.0f : 1.0f;
    slive[tid + 2 * kBlock] = ign2 ? 0.0f : 1.0f;
    slive[tid + 3 * kBlock] = ign3 ? 0.0f : 1.0f;

    float loc_sum = 0.0f, cls_sum = 0.0f, npos = 0.0f;

    // pos handling (rare; exec-masked). Reloads what it needs (L1-hot).
#define POSFIX(K) \
    if (pos##K) { \
        npos += 1.0f; \
        const int ak = a0 + K * kBlock; \
        const float4 an = *(const float4*)(iou_boxes + (size_t)ak * 4); \
        const float4 lp = *(const float4*)(loc_preds + ((size_t)b * kA + ak) * 4); \
        const float4 mb = sxywh[m##K]; \
        float ltx = (mb.x - an.x) * __builtin_amdgcn_rcpf(an.z); \
        float lty = (mb.y - an.y) * __builtin_amdgcn_rcpf(an.w); \
        float ltw = __logf(mb.z * __builtin_amdgcn_rcpf(an.z)); \
        float lth = __logf(mb.w * __builtin_amdgcn_rcpf(an.w)); \
        loc_sum += smooth_l1(lp.x - ltx) + smooth_l1(lp.y - lty) + \
                   smooth_l1(lp.z - ltw) + smooth_l1(lp.w - lth); \
        const float xc = cb[(size_t)(tid + K * kBlock) * kC + slab[m##K]]; \
        cls_sum += 0.25f * f0s(-xc) - 0.75f * f0s(xc); \
    }
    POSFIX(0) POSFIX(1) POSFIX(2) POSFIX(3)
#undef POSFIX

    __syncthreads();   // slive visible to all

    // ---- Focal stream: unit-stride chunks, slive-masked, double-buffered ----
#define S4(V) (f0s(V.x) + f0s(V.y) + f0s(V.z) + f0s(V.w))
#define DOCHUNK(P0, P1, P2, P3, P4, C) { \
    const unsigned base = (C) * kBlock; \
    acc += slive[base + (0u * kBlock + (unsigned)tid) / 5u] * S4(P0); \
    acc += slive[base + (1u * kBlock + (unsigned)tid) / 5u] * S4(P1); \
    acc += slive[base + (2u * kBlock + (unsigned)tid) / 5u] * S4(P2); \
    acc += slive[base + (3u * kBlock + (unsigned)tid) / 5u] * S4(P3); \
    acc += slive[base + (4u * kBlock + (unsigned)tid) / 5u] * S4(P4); }

    float acc = 0.0f;
    float4 q0, q1, q2, q3, q4;

    LOADCHUNK(q0, q1, q2, q3, q4, 1)
    DOCHUNK(p0, p1, p2, p3, p4, 0)
    LOADCHUNK(p0, p1, p2, p3, p4, 2)
    DOCHUNK(q0, q1, q2, q3, q4, 1)
    LOADCHUNK(q0, q1, q2, q3, q4, 3)
    DOCHUNK(p0, p1, p2, p3, p4, 2)
    DOCHUNK(q0, q1, q2, q3, q4, 3)

#undef DOCHUNK
#undef S4
#undef LOADCHUNK

    cls_sum += 0.75f * acc;

    // ---- Reduce: wave shuffle -> LDS -> per-block partial (no atomics) ----
#pragma unroll
    for (int off = 32; off > 0; off >>= 1) {
        loc_sum += __shfl_down(loc_sum, off);
        cls_sum += __shfl_down(cls_sum, off);
        npos    += __shfl_down(npos, off);
    }
    const int lane = tid & 63;
    const int wid  = tid >> 6;
    if (lane == 0) {
        sred[0][wid] = loc_sum;
        sred[1][wid] = cls_sum;
        sred[2][wid] = npos;
    }
    __syncthreads();
    if (tid == 0) {
        float l = 0.0f, c = 0.0f, n = 0.0f;
#pragma unroll
        for (int i = 0; i < kBlock / 64; ++i) {
            l += sred[0][i]; c += sred[1][i]; n += sred[2][i];
        }
        const int bid = blockIdx.y * gridDim.x + blockIdx.x;
        partial[3 * bid + 0] = l;
        partial[3 * bid + 1] = c;
        partial[3 * bid + 2] = n;
    }
}

__global__ __launch_bounds__(1024) void retina_final(
    const float* __restrict__ partial, float* __restrict__ out)
{
    __shared__ float s[3][16];
    float l = 0.0f, c = 0.0f, n = 0.0f;
    for (int i = threadIdx.x; i < kNBlocks; i += 1024) {
        l += partial[3 * i + 0];
        c += partial[3 * i + 1];
        n += partial[3 * i + 2];
    }
#pragma unroll
    for (int off = 32; off > 0; off >>= 1) {
        l += __shfl_down(l, off);
        c += __shfl_down(c, off);
        n += __shfl_down(n, off);
    }
    const int lane = threadIdx.x & 63;
    const int wid  = threadIdx.x >> 6;
    if (lane == 0) { s[0][wid] = l; s[1][wid] = c; s[2][wid] = n; }
    __syncthreads();
    if (threadIdx.x == 0) {
        float L = 0.0f, C = 0.0f, N = 0.0f;
#pragma unroll
        for (int i = 0; i < 16; ++i) { L += s[0][i]; C += s[1][i]; N += s[2][i]; }
        float np  = fmaxf(1.0f, N);
        float inv = 1.0f / np;
        out[0] = (L + C) * inv;
        out[1] = L * inv;
        out[2] = C * inv;
    }
}

}  // namespace

extern "C" void kernel_launch(void* const* d_in, const int* in_sizes, int n_in,
                              void* d_out, int out_size, void* d_ws, size_t ws_size,
                              hipStream_t stream) {
    const float* loc_preds = (const float*)d_in[0];
    const float* cls_preds = (const float*)d_in[1];
    const float* iou_boxes = (const float*)d_in[2];
    const float* targets   = (const float*)d_in[3];
    float* out     = (float*)d_out;
    float* partial = (float*)d_ws;   // 1024*3 floats, fully overwritten each call

    dim3 grid(kGridX, kB);
    retina_main<<<grid, kBlock, 0, stream>>>(loc_preds, cls_preds, iou_boxes, targets, partial);
    retina_final<<<1, 1024, 0, stream>>>(partial, out);
}